// Round 2
// baseline (2169.507 us; speedup 1.0000x reference)
//
#include <hip/hip_runtime.h>
#include <hip/hip_fp16.h>
#include <hip/hip_cooperative_groups.h>

namespace cg = cooperative_groups;

// Affinity propagation, [X=256,Y=256,Z=32] fp32, 3 iterations x 3 dirs.
//
// R10: persistent cooperative kernel. R8 (4 dispatches, 360us) vs R9
// (10 dispatches, 389us) with a ~150-190us traffic model for both implies
// ~200us of per-dispatch cost (launch + cross-XCD L2 writeback/invalidate
// between dependent dispatches, ramp/tail on 8192-wave kernels). Fuse the
// 9 propagation steps into ONE cooperative kernel with grid.sync() between
// steps; grid sized via hipOccupancyMaxActiveBlocksPerMultiprocessor so
// co-residency is guaranteed (launch_bounds(256,4) => <=128 VGPR => >=4
// blocks/CU). Also makes the kernel visible in rocprof top-5 (fills=117us).
// make_w stays a separate dispatch. Weight math / step math identical to
// the R9-proven versions. OOB semantics ride on weights==0 across edges.

constexpr int NV = 256 * 256 * 32;   // 2097152
constexpr int YZ = 256 * 32;         // 8192
constexpr int NG = NV / 4;
constexpr int GEND = 24 * NV;

struct alignas(16) H8 { __half2 h[4]; };   // 8 fp16 weights per voxel

__device__ __forceinline__ int iclamp(int v, int lo, int hi) {
    return min(max(v, lo), hi);
}

__device__ __forceinline__ void unpack8(const H8& r, float* w) {
    float2 f;
    f = __half22float2(r.h[0]); w[0] = f.x; w[1] = f.y;
    f = __half22float2(r.h[1]); w[2] = f.x; w[3] = f.y;
    f = __half22float2(r.h[2]); w[4] = f.x; w[5] = f.y;
    f = __half22float2(r.h[3]); w[6] = f.x; w[7] = f.y;
}

// ---------------- weight precompute (voxel-major store) ----------------
template <int DIR>
__device__ __forceinline__ void wgroup_t(int f0, const float* __restrict__ g,
                                         H8* __restrict__ wt) {
    constexpr int d1[8] = {1, 1, 1, 0, 0, -1, -1, -1};
    constexpr int d2[8] = {1, 0, -1, 1, -1, 1, 0, -1};
    const int z = f0 & 31, y = (f0 >> 5) & 255, x = f0 >> 13;
    const int gb0 = DIR * 8 * NV;

    float G[8][4];

    if (DIR == 0) {
#pragma unroll
        for (int k = 0; k < 8; ++k) {
            const int a = x + d1[k], b = y + d2[k];
            const bool valid = ((unsigned)a < 256u) & ((unsigned)b < 256u);
            const int ofs = f0 + d1[k] * YZ + d2[k] * 32;
            float4 gv = *(const float4*)(g + iclamp(gb0 + k * NV + ofs, 0, GEND - 4));
            if (!valid) { gv.x = 0.f; gv.y = 0.f; gv.z = 0.f; gv.w = 0.f; }
            G[k][0] = gv.x; G[k][1] = gv.y; G[k][2] = gv.z; G[k][3] = gv.w;
        }
    } else {
        const int s1 = (DIR == 1) ? YZ : 32;
        const int c1 = (DIR == 1) ? x : y;
        const bool zlo = (z > 0), zhi = (z < 28);
#pragma unroll
        for (int k = 0; k < 8; ++k) {
            const bool vrow = (unsigned)(c1 + d1[k]) < 256u;
            const int gb = gb0 + k * NV + f0 + d1[k] * s1;
            float4 gv = *(const float4*)(g + iclamp(gb, 0, GEND - 4));
            if (!vrow) { gv.x = 0.f; gv.y = 0.f; gv.z = 0.f; gv.w = 0.f; }
            if (d2[k] == 1) {
                float ge = g[iclamp(gb + 4, 0, GEND - 1)];
                ge = (vrow && zhi) ? ge : 0.f;
                G[k][0] = gv.y; G[k][1] = gv.z; G[k][2] = gv.w; G[k][3] = ge;
            } else if (d2[k] == -1) {
                float ge = g[iclamp(gb - 1, 0, GEND - 1)];
                ge = (vrow && zlo) ? ge : 0.f;
                G[k][0] = ge; G[k][1] = gv.x; G[k][2] = gv.y; G[k][3] = gv.z;
            } else {
                G[k][0] = gv.x; G[k][1] = gv.y; G[k][2] = gv.z; G[k][3] = gv.w;
            }
        }
    }

#pragma unroll
    for (int i = 0; i < 4; ++i) {
        float asum = 0.f;
#pragma unroll
        for (int k = 0; k < 8; ++k) asum += fabsf(G[k][i]);
        const float winv = __builtin_amdgcn_rcpf(asum);
        H8 rec;
#pragma unroll
        for (int p = 0; p < 4; ++p)
            rec.h[p] = __floats2half2_rn(G[2 * p][i] * winv, G[2 * p + 1][i] * winv);
        wt[DIR * NV + f0 + i] = rec;   // voxel-major: 4 consecutive records/thread
    }
}

__global__ __launch_bounds__(256) void make_w(const float* __restrict__ g,
                                              H8* __restrict__ wt) {
    const int b = blockIdx.x;
    const int dir = b >> 11;                 // 2048 blocks per dir
    const int f0 = ((b & 2047) * 256 + threadIdx.x) << 2;
    if (dir == 0)      wgroup_t<0>(f0, g, wt);
    else if (dir == 1) wgroup_t<1>(f0, g, wt);
    else               wgroup_t<2>(f0, g, wt);
}

// ---------------- one propagation step body (precomputed weights) ----------------
template <int DIR>
__device__ __forceinline__ void step_body(const H8* __restrict__ wt,
                                          const float* __restrict__ rin,
                                          float* __restrict__ rout, int f0) {
    constexpr int d1[8] = {1, 1, 1, 0, 0, -1, -1, -1};
    constexpr int d2[8] = {1, 0, -1, 1, -1, 1, 0, -1};

    // 4 weight records = 64 B contiguous per thread (4 KiB per wave)
    const H8* wp = wt + DIR * NV + f0;
    float w[4][8];
#pragma unroll
    for (int i = 0; i < 4; ++i) unpack8(wp[i], w[i]);

    float a[4];

    if (DIR == 0) {
        const float4 rc = *(const float4*)(rin + f0);
        const float rc4[4] = {rc.x, rc.y, rc.z, rc.w};
        a[0] = rc.x; a[1] = rc.y; a[2] = rc.z; a[3] = rc.w;
#pragma unroll
        for (int k = 0; k < 8; ++k) {
            const int ofs = f0 + d1[k] * YZ + d2[k] * 32;
            const float4 rv = *(const float4*)(rin + iclamp(ofs, 0, NV - 4));
            const float nb[4] = {rv.x, rv.y, rv.z, rv.w};
#pragma unroll
            for (int i = 0; i < 4; ++i)
                a[i] = fmaf(w[i][k], nb[i] - rc4[i], a[i]);
        }
    } else {
        constexpr int s1 = (DIR == 1) ? YZ : 32;
        float e[3][6];   // per x/y-row: [z-1, z0..z3, z+4]; constant-indexed only
#pragma unroll
        for (int j = 0; j < 3; ++j) {           // d1 = +1, 0, -1
            const int ro = f0 + (1 - j) * s1;
            const float4 rv = *(const float4*)(rin + iclamp(ro, 0, NV - 4));
            e[j][0] = rin[iclamp(ro - 1, 0, NV - 1)];
            e[j][1] = rv.x; e[j][2] = rv.y; e[j][3] = rv.z; e[j][4] = rv.w;
            e[j][5] = rin[iclamp(ro + 4, 0, NV - 1)];
        }
        const float rc4[4] = {e[1][1], e[1][2], e[1][3], e[1][4]};
        a[0] = rc4[0]; a[1] = rc4[1]; a[2] = rc4[2]; a[3] = rc4[3];
#pragma unroll
        for (int k = 0; k < 8; ++k) {
            const int j = 1 - d1[k];
#pragma unroll
            for (int i = 0; i < 4; ++i)
                a[i] = fmaf(w[i][k], e[j][1 + i + d2[k]] - rc4[i], a[i]);
        }
    }

    *(float4*)(rout + f0) = make_float4(a[0], a[1], a[2], a[3]);
}

// ---------------- persistent cooperative kernel: all 9 steps ----------------
__global__ __launch_bounds__(256, 4) void prop_steps(const H8* __restrict__ wt,
                                                     const float* __restrict__ blur,
                                                     float* __restrict__ bufA,
                                                     float* __restrict__ bufB,
                                                     float* __restrict__ out) {
    cg::grid_group grid = cg::this_grid();
    const int t  = threadIdx.x;
    const int nb = gridDim.x;

    const float* src = blur;
#pragma unroll 1
    for (int step = 0; step < 9; ++step) {
        float* dst = (step == 8) ? out : ((step & 1) ? bufB : bufA);
        const int d = step - (step / 3) * 3;
        for (int vb = blockIdx.x; vb < 2048; vb += nb) {
            const int f0 = (vb * 256 + t) << 2;
            if (d == 0)      step_body<0>(wt, src, dst, f0);
            else if (d == 1) step_body<1>(wt, src, dst, f0);
            else             step_body<2>(wt, src, dst, f0);
        }
        __threadfence();          // release our writes (L2 writeback, agent scope)
        grid.sync();
        __threadfence();          // acquire: invalidate stale lines before reading
        src = dst;
    }
}

// ---------------- per-step kernel (fallback if coop launch unavailable) -----
template <int DIR>
__global__ __launch_bounds__(256) void wstep(const H8* __restrict__ wt,
                                             const float* __restrict__ rin,
                                             float* __restrict__ rout) {
    const int f0 = (blockIdx.x * 256 + threadIdx.x) << 2;
    step_body<DIR>(wt, rin, rout, f0);
}

// ---------------- fallback (R1-proven): direct-from-guidance steps ----------------
template <int DIR>
__global__ __launch_bounds__(256) void prop_step(const float* __restrict__ g,
                                                 const float* __restrict__ rin,
                                                 float* __restrict__ rout) {
    constexpr int d1[8] = {1, 1, 1, 0, 0, -1, -1, -1};
    constexpr int d2[8] = {1, 0, -1, 1, -1, 1, 0, -1};
    const int t = blockIdx.x * 256 + threadIdx.x;
    const int f0 = t << 2;
    const int z = f0 & 31, y = (f0 >> 5) & 255, x = f0 >> 13;
    const int gb0 = DIR * 8 * NV;

    float as[4] = {0, 0, 0, 0}, ac[4] = {0, 0, 0, 0};
    float4 rc;

    if (DIR == 0) {
        rc = *(const float4*)(rin + f0);
#pragma unroll
        for (int k = 0; k < 8; ++k) {
            const int a = x + d1[k], b = y + d2[k];
            const bool valid = ((unsigned)a < 256u) & ((unsigned)b < 256u);
            const int ofs = f0 + d1[k] * YZ + d2[k] * 32;
            const float4 rv = *(const float4*)(rin + iclamp(ofs, 0, NV - 4));
            float4 gv = *(const float4*)(g + iclamp(gb0 + k * NV + ofs, 0, GEND - 4));
            if (!valid) { gv.x = 0.f; gv.y = 0.f; gv.z = 0.f; gv.w = 0.f; }
            as[0] += fabsf(gv.x); as[1] += fabsf(gv.y);
            as[2] += fabsf(gv.z); as[3] += fabsf(gv.w);
            ac[0] = fmaf(gv.x, rv.x - rc.x, ac[0]); ac[1] = fmaf(gv.y, rv.y - rc.y, ac[1]);
            ac[2] = fmaf(gv.z, rv.z - rc.z, ac[2]); ac[3] = fmaf(gv.w, rv.w - rc.w, ac[3]);
        }
    } else {
        const int s1 = (DIR == 1) ? YZ : 32;
        const int c1 = (DIR == 1) ? x : y;
        float4 rv[3]; float rl[3], rr[3];
#pragma unroll
        for (int j = 0; j < 3; ++j) {
            const int ro = f0 + (1 - j) * s1;
            rv[j] = *(const float4*)(rin + iclamp(ro, 0, NV - 4));
            rl[j] = rin[iclamp(ro - 1, 0, NV - 1)];
            rr[j] = rin[iclamp(ro + 4, 0, NV - 1)];
        }
        rc = rv[1];
        const bool zlo = (z > 0), zhi = (z < 28);
#pragma unroll
        for (int k = 0; k < 8; ++k) {
            const int j = 1 - d1[k];
            const bool vrow = (unsigned)(c1 + d1[k]) < 256u;
            const int gb = gb0 + k * NV + f0 + d1[k] * s1;
            float4 gv = *(const float4*)(g + iclamp(gb, 0, GEND - 4));
            if (!vrow) { gv.x = 0.f; gv.y = 0.f; gv.z = 0.f; gv.w = 0.f; }
            float4 gk, rk;
            if (d2[k] == 1) {
                float ge = g[iclamp(gb + 4, 0, GEND - 1)];
                ge = (vrow && zhi) ? ge : 0.f;
                gk = make_float4(gv.y, gv.z, gv.w, ge);
                rk = make_float4(rv[j].y, rv[j].z, rv[j].w, rr[j]);
            } else if (d2[k] == -1) {
                float ge = g[iclamp(gb - 1, 0, GEND - 1)];
                ge = (vrow && zlo) ? ge : 0.f;
                gk = make_float4(ge, gv.x, gv.y, gv.z);
                rk = make_float4(rl[j], rv[j].x, rv[j].y, rv[j].z);
            } else {
                gk = gv; rk = rv[j];
            }
            as[0] += fabsf(gk.x); as[1] += fabsf(gk.y);
            as[2] += fabsf(gk.z); as[3] += fabsf(gk.w);
            ac[0] = fmaf(gk.x, rk.x - rc.x, ac[0]); ac[1] = fmaf(gk.y, rk.y - rc.y, ac[1]);
            ac[2] = fmaf(gk.z, rk.z - rc.z, ac[2]); ac[3] = fmaf(gk.w, rk.w - rc.w, ac[3]);
        }
    }

    float4 o;
    o.x = rc.x + ac[0] * __builtin_amdgcn_rcpf(as[0]);
    o.y = rc.y + ac[1] * __builtin_amdgcn_rcpf(as[1]);
    o.z = rc.z + ac[2] * __builtin_amdgcn_rcpf(as[2]);
    o.w = rc.w + ac[3] * __builtin_amdgcn_rcpf(as[3]);
    *(float4*)(rout + f0) = o;
}

extern "C" void kernel_launch(void* const* d_in, const int* in_sizes, int n_in,
                              void* d_out, int out_size, void* d_ws, size_t ws_size,
                              hipStream_t stream) {
    const float* g    = (const float*)d_in[0];
    const float* blur = (const float*)d_in[1];
    float* out = (float*)d_out;

    const size_t WBYTES = (size_t)3 * NV * sizeof(H8);            // 96 MiB
    const size_t NEED   = WBYTES + (size_t)2 * NV * sizeof(float);

    if (ws_size >= NEED) {
        H8*    wt   = (H8*)d_ws;
        float* bufA = (float*)((char*)d_ws + WBYTES);
        float* bufB = bufA + NV;

        make_w<<<dim3(3 * NG / 256), dim3(256), 0, stream>>>(g, wt);

        // Decide cooperative grid size once (occupancy-validated, no deadlock).
        static int s_blocks = -2;   // -2 uninit, -1 unavailable
        if (s_blocks == -2) {
            s_blocks = -1;
            int dev = 0;
            if (hipGetDevice(&dev) == hipSuccess) {
                int coop = 0, ncu = 0, bpc = 0;
                hipDeviceGetAttribute(&coop, hipDeviceAttributeCooperativeLaunch, dev);
                hipDeviceGetAttribute(&ncu, hipDeviceAttributeMultiprocessorCount, dev);
                if (coop && ncu > 0 &&
                    hipOccupancyMaxActiveBlocksPerMultiprocessor(
                        &bpc, prop_steps, 256, 0) == hipSuccess && bpc > 0) {
                    long nb = (long)ncu * (long)bpc;
                    if (nb > 2048) nb = 2048;
                    if (nb >= 64) s_blocks = (int)nb;
                }
            }
        }

        bool done = false;
        if (s_blocks > 0) {
            const H8* wtc = wt;
            const float* bl = blur;
            float* pA = bufA; float* pB = bufB; float* po = out;
            void* args[] = {(void*)&wtc, (void*)&bl, (void*)&pA, (void*)&pB, (void*)&po};
            hipError_t e = hipLaunchCooperativeKernel((const void*)prop_steps,
                                                      dim3(s_blocks), dim3(256),
                                                      args, 0, stream);
            done = (e == hipSuccess);
        }

        if (!done) {
            // fallback: R9-proven 9 streaming dispatches
            const float* src = blur;
            for (int step = 0; step < 9; ++step) {
                float* dst = (step == 8) ? out : ((step & 1) ? bufB : bufA);
                switch (step % 3) {
                    case 0: wstep<0><<<dim3(NG / 256), dim3(256), 0, stream>>>(wt, src, dst); break;
                    case 1: wstep<1><<<dim3(NG / 256), dim3(256), 0, stream>>>(wt, src, dst); break;
                    case 2: wstep<2><<<dim3(NG / 256), dim3(256), 0, stream>>>(wt, src, dst); break;
                }
                src = dst;
            }
        }
    } else {
        // fallback: R1-proven direct path (needs only 8 MiB of ws)
        float* ws = (float*)d_ws;
        const dim3 block(256), sgrid(NG / 256);
        const float* src = blur;
        for (int step = 0; step < 9; ++step) {
            float* dst = (step & 1) ? ws : out;
            switch (step % 3) {
                case 0: prop_step<0><<<sgrid, block, 0, stream>>>(g, src, dst); break;
                case 1: prop_step<1><<<sgrid, block, 0, stream>>>(g, src, dst); break;
                case 2: prop_step<2><<<sgrid, block, 0, stream>>>(g, src, dst); break;
            }
            src = dst;
        }
    }
}

// Round 4
// 414.067 us; speedup vs baseline: 5.2395x; 5.2395x over previous
//
#include <hip/hip_runtime.h>
#include <hip/hip_fp16.h>

// Affinity propagation, [X=256,Y=256,Z=32] fp32, 3 iterations x 3 dirs.
//
// R12 = R11 with the LDS column swizzle REMOVED. R11's cbase() swizzle
// (+((c>>3)&7)*4 over a stride-24 grid) was non-bijective: at each 64-col
// wrap the offset drops 28->0, so columns 63/64 (127/128, 191/192) overlap
// by 20 slots => data corruption (absmax 459). Pure stride-24 columns are
// bijective; cost is 2x LDS b128 banking (bases 1+6c in float4 units hit
// only 4 of 8 bank-quads) ~= +5-10us/iter, second-order vs the 96 MiB/iter
// weight stream. Structure (from R11):
//   - 4 dispatches total: make_w + 3x fused-iteration (R10 proved software
//     grid-sync costs 200-500us/sync; ~30us/dispatch boundary measured).
//   - z-chunked tile (2 chunks, slot depth 24, halo 2/side): LDS 40.4 KB
//     => 4 blocks/CU, grid 1024 fully resident.
//   - slot-phase design keeps every LDS float4 access 16B-aligned:
//     r at slots (chunk?0:4)+0..19 (abs z = z0+slot-4), d0/d1 compute
//     j=0..5 on slots 4j..4j+3, d2 computes j=0..3 on slots 4+4j..7+4j
//     (= abs z0+4j) and stores those 16 z directly to global.
// Edge semantics: OOB/garbage neighbor values are finite (zero-init LDS,
// guard slots) and always multiplied by weight==0 (make_w zeroes edge
// weights) — the R8/R9-proven scheme. Chunk-boundary z values real (halo 2).

constexpr int NV = 256 * 256 * 32;   // 2097152
constexpr int YZ = 256 * 32;         // 8192
constexpr int NG = NV / 4;
constexpr int GEND = 24 * NV;

constexpr int TXB = 8, TYB = 16;     // output tile per block (xy)
constexpr int RXD = 12, RYD = 20;    // region dims (halo 2 each side)
constexpr int NCOL = RXD * RYD;      // 240 columns
constexpr int ZSTR = 24;             // slots per column (16 out + 2+2 halo + phase pad)
constexpr int LOFFG = 4;             // front guard floats (slot -1 reads)
constexpr int ASZP = LOFFG + 240 * ZSTR + 12;   // 5776 floats
constexpr int BSZP = LOFFG + 180 * ZSTR + 12;   // 4336 floats
// total LDS = (5776+4336)*4 = 40448 B => 4 blocks/CU on 160 KiB

struct alignas(16) H8 { __half2 h[4]; };   // 8 fp16 weights per voxel

__device__ __forceinline__ int iclamp(int v, int lo, int hi) {
    return min(max(v, lo), hi);
}

__device__ __forceinline__ int cbase(int c) {   // column base (bijective!)
    return LOFFG + c * ZSTR;
}

__device__ __forceinline__ void unpack8(const H8& r, float* w) {
    float2 f;
    f = __half22float2(r.h[0]); w[0] = f.x; w[1] = f.y;
    f = __half22float2(r.h[1]); w[2] = f.x; w[3] = f.y;
    f = __half22float2(r.h[2]); w[4] = f.x; w[5] = f.y;
    f = __half22float2(r.h[3]); w[6] = f.x; w[7] = f.y;
}

// ---------------- weight precompute (voxel-major store) ----------------
template <int DIR>
__device__ __forceinline__ void wgroup_t(int f0, const float* __restrict__ g,
                                         H8* __restrict__ wt) {
    constexpr int d1[8] = {1, 1, 1, 0, 0, -1, -1, -1};
    constexpr int d2[8] = {1, 0, -1, 1, -1, 1, 0, -1};
    const int z = f0 & 31, y = (f0 >> 5) & 255, x = f0 >> 13;
    const int gb0 = DIR * 8 * NV;

    float G[8][4];

    if (DIR == 0) {
#pragma unroll
        for (int k = 0; k < 8; ++k) {
            const int a = x + d1[k], b = y + d2[k];
            const bool valid = ((unsigned)a < 256u) & ((unsigned)b < 256u);
            const int ofs = f0 + d1[k] * YZ + d2[k] * 32;
            float4 gv = *(const float4*)(g + iclamp(gb0 + k * NV + ofs, 0, GEND - 4));
            if (!valid) { gv.x = 0.f; gv.y = 0.f; gv.z = 0.f; gv.w = 0.f; }
            G[k][0] = gv.x; G[k][1] = gv.y; G[k][2] = gv.z; G[k][3] = gv.w;
        }
    } else {
        const int s1 = (DIR == 1) ? YZ : 32;
        const int c1 = (DIR == 1) ? x : y;
        const bool zlo = (z > 0), zhi = (z < 28);
#pragma unroll
        for (int k = 0; k < 8; ++k) {
            const bool vrow = (unsigned)(c1 + d1[k]) < 256u;
            const int gb = gb0 + k * NV + f0 + d1[k] * s1;
            float4 gv = *(const float4*)(g + iclamp(gb, 0, GEND - 4));
            if (!vrow) { gv.x = 0.f; gv.y = 0.f; gv.z = 0.f; gv.w = 0.f; }
            if (d2[k] == 1) {
                float ge = g[iclamp(gb + 4, 0, GEND - 1)];
                ge = (vrow && zhi) ? ge : 0.f;
                G[k][0] = gv.y; G[k][1] = gv.z; G[k][2] = gv.w; G[k][3] = ge;
            } else if (d2[k] == -1) {
                float ge = g[iclamp(gb - 1, 0, GEND - 1)];
                ge = (vrow && zlo) ? ge : 0.f;
                G[k][0] = ge; G[k][1] = gv.x; G[k][2] = gv.y; G[k][3] = gv.z;
            } else {
                G[k][0] = gv.x; G[k][1] = gv.y; G[k][2] = gv.z; G[k][3] = gv.w;
            }
        }
    }

#pragma unroll
    for (int i = 0; i < 4; ++i) {
        float asum = 0.f;
#pragma unroll
        for (int k = 0; k < 8; ++k) asum += fabsf(G[k][i]);
        const float winv = __builtin_amdgcn_rcpf(asum);
        H8 rec;
#pragma unroll
        for (int p = 0; p < 4; ++p)
            rec.h[p] = __floats2half2_rn(G[2 * p][i] * winv, G[2 * p + 1][i] * winv);
        wt[DIR * NV + f0 + i] = rec;   // voxel-major: 4 consecutive records/thread
    }
}

__global__ __launch_bounds__(256) void make_w(const float* __restrict__ g,
                                              H8* __restrict__ wt) {
    const int b = blockIdx.x;
    const int dir = b >> 11;                 // 2048 blocks per dir
    const int f0 = ((b & 2047) * 256 + threadIdx.x) << 2;
    if (dir == 0)      wgroup_t<0>(f0, g, wt);
    else if (dir == 1) wgroup_t<1>(f0, g, wt);
    else               wgroup_t<2>(f0, g, wt);
}

// ---------------- fused 3-step iteration kernel (z-chunked) ----------------
__global__ __launch_bounds__(256, 4) void iter_fused(const H8* __restrict__ wt,
                                                     const float* __restrict__ rin,
                                                     float* __restrict__ rout) {
    __shared__ __align__(16) float A[ASZP];
    __shared__ __align__(16) float B[BSZP];
    constexpr int d1c[8] = {1, 1, 1, 0, 0, -1, -1, -1};
    constexpr int d2c[8] = {1, 0, -1, 1, -1, 1, 0, -1};

    const int t = threadIdx.x;
    const int chunk = blockIdx.x & 1;
    const int tile  = blockIdx.x >> 1;
    const int bx = tile & 31, by = tile >> 5;      // 32 x 16 tiles
    const bool act = t < NCOL;
    const int rx = t / RYD, ry = t - rx * RYD;
    const int gx = bx * TXB - 2 + rx, gy = by * TYB - 2 + ry;
    const int gxc = iclamp(gx, 0, 255), gyc = iclamp(gy, 0, 255);
    const int z0 = chunk * 16;
    const int slot_base = chunk ? 0 : 4;   // abs z of slot s is z0 + s - 4
    const int gz_base   = chunk ? 12 : 0;

    for (int i = t; i < ASZP; i += 256) A[i] = 0.f;
    for (int i = t; i < BSZP; i += 256) B[i] = 0.f;
    __syncthreads();

    // r tile load: 20 contiguous floats/column, 16B-aligned both sides.
    if (act) {
        const float* p = rin + ((gxc << 8) + gyc) * 32 + gz_base;
        const int ab = cbase(t) + slot_base;
#pragma unroll
        for (int j = 0; j < 5; ++j)
            *(float4*)(A + ab + 4 * j) = *(const float4*)(p + 4 * j);
    }
    __syncthreads();

    const bool in0 = act && rx >= 1 && rx <= 10 && ry >= 1 && ry <= 18;
    const bool in1 = act && rx >= 2 && rx <= 9  && ry >= 1 && ry <= 18;
    const bool in2 = act && rx >= 2 && rx <= 9  && ry >= 2 && ry <= 17;
    const int wvox = ((gxc << 8) + gyc) * 32;

    // ---- step d0: xy-neighbors, A(r) -> B ----
    if (in0) {
        int nbb[8];
#pragma unroll
        for (int k = 0; k < 8; ++k)
            nbb[k] = cbase((rx + d1c[k]) * RYD + (ry + d2c[k]));
        const int ab = cbase(t);
        const int bb = cbase((rx - 1) * 18 + (ry - 1));
        const H8* wp = wt + wvox;                       // dir0
#pragma unroll
        for (int j = 0; j < 6; ++j) {
            const int zs = z0 - 4 + 4 * j;
            H8 wr[4];
#pragma unroll
            for (int i = 0; i < 4; ++i) wr[i] = wp[iclamp(zs + i, 0, 31)];
            const float4 vc = *(const float4*)(A + ab + 4 * j);
            const float rc4[4] = {vc.x, vc.y, vc.z, vc.w};
            float nb[8][4];
#pragma unroll
            for (int k = 0; k < 8; ++k) {
                const float4 v = *(const float4*)(A + nbb[k] + 4 * j);
                nb[k][0] = v.x; nb[k][1] = v.y; nb[k][2] = v.z; nb[k][3] = v.w;
            }
            float o[4];
#pragma unroll
            for (int i = 0; i < 4; ++i) {
                float w[8]; unpack8(wr[i], w);
                float a = rc4[i];
#pragma unroll
                for (int k = 0; k < 8; ++k) a = fmaf(w[k], nb[k][i] - rc4[i], a);
                o[i] = a;
            }
            *(float4*)(B + bb + 4 * j) = make_float4(o[0], o[1], o[2], o[3]);
        }
    }
    __syncthreads();

    // ---- step d1: x,z-neighbors, B -> A (overwrite own column) ----
    if (in1) {
        const int rowb[3] = {cbase(rx * 18 + (ry - 1)),          // x+1
                             cbase((rx - 1) * 18 + (ry - 1)),    // x
                             cbase((rx - 2) * 18 + (ry - 1))};   // x-1
        const int ab = cbase(t);
        const H8* wp = wt + NV + wvox;                  // dir1
#pragma unroll
        for (int j = 0; j < 6; ++j) {
            const int zs = z0 - 4 + 4 * j;
            H8 wr[4];
#pragma unroll
            for (int i = 0; i < 4; ++i) wr[i] = wp[iclamp(zs + i, 0, 31)];
            float e[3][6];
#pragma unroll
            for (int jr = 0; jr < 3; ++jr) {
                const int cofs = rowb[jr] + 4 * j;
                const float4 v = *(const float4*)(B + cofs);
                e[jr][0] = B[cofs - 1];
                e[jr][1] = v.x; e[jr][2] = v.y; e[jr][3] = v.z; e[jr][4] = v.w;
                e[jr][5] = B[cofs + 4];
            }
            float o[4];
#pragma unroll
            for (int i = 0; i < 4; ++i) {
                float w[8]; unpack8(wr[i], w);
                const float rc = e[1][1 + i];
                float a = rc;
#pragma unroll
                for (int k = 0; k < 8; ++k)
                    a = fmaf(w[k], e[1 - d1c[k]][1 + i + d2c[k]] - rc, a);
                o[i] = a;
            }
            *(float4*)(A + ab + 4 * j) = make_float4(o[0], o[1], o[2], o[3]);
        }
    }
    __syncthreads();

    // ---- step d2: y,z-neighbors, A -> global (slots 4..19 = abs z0..z0+15) ----
    if (in2) {
        const int rowb[3] = {cbase(rx * RYD + (ry + 1)),   // y+1
                             cbase(rx * RYD + ry),         // y
                             cbase(rx * RYD + (ry - 1))};  // y-1
        const H8* wp = wt + 2 * NV + wvox;              // dir2
        float* gq = rout + ((gx << 8) + gy) * 32 + z0;
#pragma unroll
        for (int j = 0; j < 4; ++j) {
            const int zs = z0 + 4 * j;                  // always in [0,31]
            H8 wr[4];
#pragma unroll
            for (int i = 0; i < 4; ++i) wr[i] = wp[zs + i];
            float e[3][6];
#pragma unroll
            for (int jr = 0; jr < 3; ++jr) {
                const int cofs = rowb[jr] + 4 + 4 * j;
                const float4 v = *(const float4*)(A + cofs);
                e[jr][0] = A[cofs - 1];
                e[jr][1] = v.x; e[jr][2] = v.y; e[jr][3] = v.z; e[jr][4] = v.w;
                e[jr][5] = A[cofs + 4];
            }
            float o[4];
#pragma unroll
            for (int i = 0; i < 4; ++i) {
                float w[8]; unpack8(wr[i], w);
                const float rc = e[1][1 + i];
                float a = rc;
#pragma unroll
                for (int k = 0; k < 8; ++k)
                    a = fmaf(w[k], e[1 - d1c[k]][1 + i + d2c[k]] - rc, a);
                o[i] = a;
            }
            *(float4*)(gq + 4 * j) = make_float4(o[0], o[1], o[2], o[3]);
        }
    }
}

// ---------------- per-step kernel (R9-proven, fallback) ----------------
template <int DIR>
__device__ __forceinline__ void step_body(const H8* __restrict__ wt,
                                          const float* __restrict__ rin,
                                          float* __restrict__ rout, int f0) {
    constexpr int d1[8] = {1, 1, 1, 0, 0, -1, -1, -1};
    constexpr int d2[8] = {1, 0, -1, 1, -1, 1, 0, -1};

    const H8* wp = wt + DIR * NV + f0;
    float w[4][8];
#pragma unroll
    for (int i = 0; i < 4; ++i) unpack8(wp[i], w[i]);

    float a[4];

    if (DIR == 0) {
        const float4 rc = *(const float4*)(rin + f0);
        const float rc4[4] = {rc.x, rc.y, rc.z, rc.w};
        a[0] = rc.x; a[1] = rc.y; a[2] = rc.z; a[3] = rc.w;
#pragma unroll
        for (int k = 0; k < 8; ++k) {
            const int ofs = f0 + d1[k] * YZ + d2[k] * 32;
            const float4 rv = *(const float4*)(rin + iclamp(ofs, 0, NV - 4));
            const float nb[4] = {rv.x, rv.y, rv.z, rv.w};
#pragma unroll
            for (int i = 0; i < 4; ++i)
                a[i] = fmaf(w[i][k], nb[i] - rc4[i], a[i]);
        }
    } else {
        constexpr int s1 = (DIR == 1) ? YZ : 32;
        float e[3][6];
#pragma unroll
        for (int j = 0; j < 3; ++j) {
            const int ro = f0 + (1 - j) * s1;
            const float4 rv = *(const float4*)(rin + iclamp(ro, 0, NV - 4));
            e[j][0] = rin[iclamp(ro - 1, 0, NV - 1)];
            e[j][1] = rv.x; e[j][2] = rv.y; e[j][3] = rv.z; e[j][4] = rv.w;
            e[j][5] = rin[iclamp(ro + 4, 0, NV - 1)];
        }
        const float rc4[4] = {e[1][1], e[1][2], e[1][3], e[1][4]};
        a[0] = rc4[0]; a[1] = rc4[1]; a[2] = rc4[2]; a[3] = rc4[3];
#pragma unroll
        for (int k = 0; k < 8; ++k) {
            const int j = 1 - d1[k];
#pragma unroll
            for (int i = 0; i < 4; ++i)
                a[i] = fmaf(w[i][k], e[j][1 + i + d2[k]] - rc4[i], a[i]);
        }
    }

    *(float4*)(rout + f0) = make_float4(a[0], a[1], a[2], a[3]);
}

template <int DIR>
__global__ __launch_bounds__(256) void wstep(const H8* __restrict__ wt,
                                             const float* __restrict__ rin,
                                             float* __restrict__ rout) {
    const int f0 = (blockIdx.x * 256 + threadIdx.x) << 2;
    step_body<DIR>(wt, rin, rout, f0);
}

// ---------------- fallback (R1-proven): direct-from-guidance steps ----------------
template <int DIR>
__global__ __launch_bounds__(256) void prop_step(const float* __restrict__ g,
                                                 const float* __restrict__ rin,
                                                 float* __restrict__ rout) {
    constexpr int d1[8] = {1, 1, 1, 0, 0, -1, -1, -1};
    constexpr int d2[8] = {1, 0, -1, 1, -1, 1, 0, -1};
    const int t = blockIdx.x * 256 + threadIdx.x;
    const int f0 = t << 2;
    const int z = f0 & 31, y = (f0 >> 5) & 255, x = f0 >> 13;
    const int gb0 = DIR * 8 * NV;

    float as[4] = {0, 0, 0, 0}, ac[4] = {0, 0, 0, 0};
    float4 rc;

    if (DIR == 0) {
        rc = *(const float4*)(rin + f0);
#pragma unroll
        for (int k = 0; k < 8; ++k) {
            const int a = x + d1[k], b = y + d2[k];
            const bool valid = ((unsigned)a < 256u) & ((unsigned)b < 256u);
            const int ofs = f0 + d1[k] * YZ + d2[k] * 32;
            const float4 rv = *(const float4*)(rin + iclamp(ofs, 0, NV - 4));
            float4 gv = *(const float4*)(g + iclamp(gb0 + k * NV + ofs, 0, GEND - 4));
            if (!valid) { gv.x = 0.f; gv.y = 0.f; gv.z = 0.f; gv.w = 0.f; }
            as[0] += fabsf(gv.x); as[1] += fabsf(gv.y);
            as[2] += fabsf(gv.z); as[3] += fabsf(gv.w);
            ac[0] = fmaf(gv.x, rv.x - rc.x, ac[0]); ac[1] = fmaf(gv.y, rv.y - rc.y, ac[1]);
            ac[2] = fmaf(gv.z, rv.z - rc.z, ac[2]); ac[3] = fmaf(gv.w, rv.w - rc.w, ac[3]);
        }
    } else {
        const int s1 = (DIR == 1) ? YZ : 32;
        const int c1 = (DIR == 1) ? x : y;
        float4 rv[3]; float rl[3], rr[3];
#pragma unroll
        for (int j = 0; j < 3; ++j) {
            const int ro = f0 + (1 - j) * s1;
            rv[j] = *(const float4*)(rin + iclamp(ro, 0, NV - 4));
            rl[j] = rin[iclamp(ro - 1, 0, NV - 1)];
            rr[j] = rin[iclamp(ro + 4, 0, NV - 1)];
        }
        rc = rv[1];
        const bool zlo = (z > 0), zhi = (z < 28);
#pragma unroll
        for (int k = 0; k < 8; ++k) {
            const int j = 1 - d1[k];
            const bool vrow = (unsigned)(c1 + d1[k]) < 256u;
            const int gb = gb0 + k * NV + f0 + d1[k] * s1;
            float4 gv = *(const float4*)(g + iclamp(gb, 0, GEND - 4));
            if (!vrow) { gv.x = 0.f; gv.y = 0.f; gv.z = 0.f; gv.w = 0.f; }
            float4 gk, rk;
            if (d2[k] == 1) {
                float ge = g[iclamp(gb + 4, 0, GEND - 1)];
                ge = (vrow && zhi) ? ge : 0.f;
                gk = make_float4(gv.y, gv.z, gv.w, ge);
                rk = make_float4(rv[j].y, rv[j].z, rv[j].w, rr[j]);
            } else if (d2[k] == -1) {
                float ge = g[iclamp(gb - 1, 0, GEND - 1)];
                ge = (vrow && zlo) ? ge : 0.f;
                gk = make_float4(ge, gv.x, gv.y, gv.z);
                rk = make_float4(rl[j], rv[j].x, rv[j].y, rv[j].z);
            } else {
                gk = gv; rk = rv[j];
            }
            as[0] += fabsf(gk.x); as[1] += fabsf(gk.y);
            as[2] += fabsf(gk.z); as[3] += fabsf(gk.w);
            ac[0] = fmaf(gk.x, rk.x - rc.x, ac[0]); ac[1] = fmaf(gk.y, rk.y - rc.y, ac[1]);
            ac[2] = fmaf(gk.z, rk.z - rc.z, ac[2]); ac[3] = fmaf(gk.w, rk.w - rc.w, ac[3]);
        }
    }

    float4 o;
    o.x = rc.x + ac[0] * __builtin_amdgcn_rcpf(as[0]);
    o.y = rc.y + ac[1] * __builtin_amdgcn_rcpf(as[1]);
    o.z = rc.z + ac[2] * __builtin_amdgcn_rcpf(as[2]);
    o.w = rc.w + ac[3] * __builtin_amdgcn_rcpf(as[3]);
    *(float4*)(rout + f0) = o;
}

extern "C" void kernel_launch(void* const* d_in, const int* in_sizes, int n_in,
                              void* d_out, int out_size, void* d_ws, size_t ws_size,
                              hipStream_t stream) {
    const float* g    = (const float*)d_in[0];
    const float* blur = (const float*)d_in[1];
    float* out = (float*)d_out;

    const size_t WBYTES = (size_t)3 * NV * sizeof(H8);            // 96 MiB
    const size_t NEED   = WBYTES + (size_t)2 * NV * sizeof(float);

    if (ws_size >= NEED) {
        H8*    wt   = (H8*)d_ws;
        float* bufA = (float*)((char*)d_ws + WBYTES);
        float* bufB = bufA + NV;

        make_w<<<dim3(3 * NG / 256), dim3(256), 0, stream>>>(g, wt);
        iter_fused<<<dim3(1024), dim3(256), 0, stream>>>(wt, blur, bufA);
        iter_fused<<<dim3(1024), dim3(256), 0, stream>>>(wt, bufA, bufB);
        iter_fused<<<dim3(1024), dim3(256), 0, stream>>>(wt, bufB, out);
    } else {
        // fallback: R1-proven direct path (needs only 8 MiB of ws)
        float* ws = (float*)d_ws;
        const dim3 block(256), sgrid(NG / 256);
        const float* src = blur;
        for (int step = 0; step < 9; ++step) {
            float* dst = (step & 1) ? ws : out;
            switch (step % 3) {
                case 0: prop_step<0><<<sgrid, block, 0, stream>>>(g, src, dst); break;
                case 1: prop_step<1><<<sgrid, block, 0, stream>>>(g, src, dst); break;
                case 2: prop_step<2><<<sgrid, block, 0, stream>>>(g, src, dst); break;
            }
            src = dst;
        }
    }
}